// Round 2
// baseline (2289.912 us; speedup 1.0000x reference)
//
#include <hip/hip_runtime.h>
#include <hip/hip_cooperative_groups.h>
#include <math.h>

namespace cg = cooperative_groups;

#define B_ 64
#define T_ 128
#define I_ 1024
#define H_ 4096
#define XCDS 8

#define RNN_BLOCKS 256
#define RNN_THREADS 1024

#define MAXIT_HH 12   // 96 nnz/row registerized (Poisson(64): P(len>96) ~ 1e-4 -> tail fallback)
#define MAXIT_IH 8    // 64 nnz/row registerized (Poisson(32))

// ---------------- helpers ----------------
__device__ __forceinline__ unsigned short f2bf(float f) {
    unsigned int u = __float_as_uint(f);
    unsigned int r = (u + 0x7fffu + ((u >> 16) & 1u)) >> 16;
    return (unsigned short)r;
}

__device__ __forceinline__ void load4x16_sc0(const float* p0, const float* p1,
                                             const float* p2, const float* p3,
                                             float4& a, float4& b, float4& c, float4& d) {
    asm volatile(
        "global_load_dwordx4 %0, %4, off sc0\n\t"
        "global_load_dwordx4 %1, %5, off sc0\n\t"
        "global_load_dwordx4 %2, %6, off sc0\n\t"
        "global_load_dwordx4 %3, %7, off sc0\n\t"
        "s_waitcnt vmcnt(0)"
        : "=&v"(a), "=&v"(b), "=&v"(c), "=&v"(d)
        : "v"(p0), "v"(p1), "v"(p2), "v"(p3));
}

// ---------------- transpose x (B,T,I) -> xT2 (T, 8, I, 8) ----------------
__global__ void transpose_x(const float* __restrict__ x, float* __restrict__ xT2) {
    __shared__ float lds[8][129];
    int t  = blockIdx.z;
    int bg = blockIdx.y;
    int i0 = blockIdx.x * 128;
    int tx = threadIdx.x;   // 0..127
    int ty = threadIdx.y;   // 0..7
    int b = bg * 8 + ty;
    lds[ty][tx] = x[(size_t)b * T_ * I_ + (size_t)t * I_ + i0 + tx];
    __syncthreads();
    int n  = ty * 128 + tx;
    int ii = n >> 3;
    int bs = n & 7;
    xT2[(((size_t)t * 8 + bg) * I_ + i0 + ii) * 8 + bs] = lds[bs][ii];
}

// ---------------- CSR build ----------------
__global__ void hist_rows(const int* __restrict__ rows, int nnz, int* __restrict__ counts) {
    int k = blockIdx.x * blockDim.x + threadIdx.x;
    if (k < nnz) atomicAdd(&counts[rows[k]], 1);
}

__global__ void scan_rows(const int* __restrict__ counts, int* __restrict__ rp, int n) {
    int lane = threadIdx.x;      // 0..63
    int chunk = n / 64;
    int base = lane * chunk;
    int s = 0;
    for (int j = 0; j < chunk; ++j) s += counts[base + j];
    int pre = s;
    for (int off = 1; off < 64; off <<= 1) {
        int up = __shfl_up(pre, off, 64);
        if (lane >= off) pre += up;
    }
    int run = pre - s;
    for (int j = 0; j < chunk; ++j) { rp[base + j] = run; run += counts[base + j]; }
    if (lane == 63) rp[n] = run;
}

__global__ void scatter_pack(const int* __restrict__ rows, const int* __restrict__ cols,
                             const float* __restrict__ vals, int nnz,
                             const int* __restrict__ rp, int* __restrict__ cursor,
                             int2* __restrict__ pack) {
    int k = blockIdx.x * blockDim.x + threadIdx.x;
    if (k < nnz) {
        int r = rows[k];
        int pos = atomicAdd(&cursor[r], 1);
        pack[rp[r] + pos] = make_int2(cols[k], __float_as_int(vals[k]));
    }
}

// ---------------- kernel P: pre[t] = W_ih * x_t + bias  (bf16 out) ----------------
// One block per (8 row-groups, grp); t-loop inside. CSR slices registerized
// (t-invariant), x_t slice staged in LDS (32 KB), 2 row-groups per wave.
__global__ __launch_bounds__(256)
void precompute_ih(const float* __restrict__ xT2,
                   const int* __restrict__ rp, const int2* __restrict__ pack,
                   const float* __restrict__ bias,
                   unsigned short* __restrict__ pre) {
    __shared__ __align__(16) float xs[I_ * 8];   // 32 KB: x_t slice for this grp
    int grp  = blockIdx.y;
    int wave = threadIdx.x >> 6;                  // 0..3
    int lane = threadIdx.x & 63;
    int rs = lane >> 3;   // row within group
    int u  = lane & 7;    // position within window

    int gg[2];
    gg[0] = blockIdx.x * 8 + 2 * wave;
    gg[1] = blockIdx.x * 8 + 2 * wave + 1;

    int   hbv[2], lenv[2], lmaxv[2];
    float bsv[2];
    int   pcol[2][MAXIT_IH];
    float pval[2][MAXIT_IH];
    #pragma unroll
    for (int q = 0; q < 2; ++q) {
        int r = gg[q] * 8 + rs;
        hbv[q] = rp[r];
        lenv[q] = rp[r + 1] - hbv[q];
        int lm = lenv[q];
        lm = max(lm, __shfl_xor(lm, 8));
        lm = max(lm, __shfl_xor(lm, 16));
        lm = max(lm, __shfl_xor(lm, 32));
        lmaxv[q] = __builtin_amdgcn_readfirstlane(lm);
        bsv[q] = bias[r];
        #pragma unroll
        for (int it = 0; it < MAXIT_IH; ++it) {
            int2 pk = make_int2(0, 0);
            if (it * 8 + u < lenv[q]) pk = pack[hbv[q] + it * 8 + u];
            pcol[q][it] = pk.x << 5;              // col * 8 floats * 4 B
            pval[q][it] = __int_as_float(pk.y);
        }
    }

    for (int t = 0; t < T_; ++t) {
        const float* xt = xT2 + ((size_t)t * 8 + grp) * (I_ * 8);
        __syncthreads();    // prior step's reads of xs done
        {
            const float4* s = (const float4*)xt;
            float4* d = (float4*)xs;
            #pragma unroll
            for (int j = 0; j < 8; ++j)
                d[j * 256 + threadIdx.x] = s[j * 256 + threadIdx.x];
        }
        __syncthreads();    // xs ready

        #pragma unroll
        for (int q = 0; q < 2; ++q) {
            float a[8];
            #pragma unroll
            for (int j = 0; j < 8; ++j) a[j] = 0.0f;

            // branchless registerized windows (padded lanes read xs[0], add +0.0)
            #pragma unroll
            for (int it = 0; it < MAXIT_IH; ++it) {
                const float* gp = (const float*)((const char*)xs + pcol[q][it]);
                float4 x0 = *(const float4*)gp;
                float4 x1 = *(const float4*)(gp + 4);
                float v = pval[q][it];
                a[0] += v * x0.x; a[1] += v * x0.y; a[2] += v * x0.z; a[3] += v * x0.w;
                a[4] += v * x1.x; a[5] += v * x1.y; a[6] += v * x1.z; a[7] += v * x1.w;
            }
            if (lmaxv[q] > 8 * MAXIT_IH) {   // rare tail, same summation order
                int kk = hbv[q] + 8 * MAXIT_IH + u;
                for (int i = 8 * MAXIT_IH; i < lmaxv[q]; i += 8, kk += 8) {
                    int2 pk = make_int2(0, 0);
                    if (i + u < lenv[q]) pk = pack[kk];
                    const float* gp = (const float*)((const char*)xs + ((size_t)pk.x << 5));
                    float4 x0 = *(const float4*)gp;
                    float4 x1 = *(const float4*)(gp + 4);
                    float v = __int_as_float(pk.y);
                    a[0] += v * x0.x; a[1] += v * x0.y; a[2] += v * x0.z; a[3] += v * x0.w;
                    a[4] += v * x1.x; a[5] += v * x1.y; a[6] += v * x1.z; a[7] += v * x1.w;
                }
            }
            #pragma unroll
            for (int off = 1; off <= 4; off <<= 1) {
                #pragma unroll
                for (int j = 0; j < 8; ++j) a[j] += __shfl_xor(a[j], off);
            }
            float sel = (u == 0) ? a[0] : (u == 1) ? a[1] : (u == 2) ? a[2] : (u == 3) ? a[3]
                      : (u == 4) ? a[4] : (u == 5) ? a[5] : (u == 6) ? a[6] : a[7];
            float p = sel + bsv[q];
            int hf = u >> 2, cc = u & 3;
            int r = gg[q] * 8 + rs;
            pre[((size_t)(grp * 2 + hf) * T_ + t) * (H_ * 4) + (size_t)r * 4 + cc] = f2bf(p);
        }
    }
}

// ---------------- kernel R: persistent XCD-local recurrence ----------------
// hg layout: hg[((grp*2 + parity)*2 + half) * (H_*4)]
__global__ __launch_bounds__(RNN_THREADS, 1)
void rnn_steps(const int* __restrict__ hhp, const int2* __restrict__ hhpack,
               const unsigned short* __restrict__ pre,
               float* __restrict__ hg,
               int* __restrict__ regcnt, int* __restrict__ barcnt, int* __restrict__ bargen,
               int* __restrict__ owncnt, int* __restrict__ owngrp,
               float* __restrict__ out) {
    cg::grid_group grid = cg::this_grid();
    __shared__ __align__(16) float sh[H_ * 4];   // 64 KB: h_prev, 4 batch cols of this half

    int tid = threadIdx.x;
    if (tid == 0) {
        int x;
        asm volatile("s_getreg_b32 %0, hwreg(HW_REG_XCC_ID)" : "=s"(x));
        x &= 7;
        int slot = __hip_atomic_fetch_add(&regcnt[x], 1, __ATOMIC_RELAXED,
                                          __HIP_MEMORY_SCOPE_AGENT);
        sh[0] = __int_as_float(x);
        sh[1] = __int_as_float(slot);
    }
    __syncthreads();
    int xcd  = __float_as_int(sh[0]);
    int slot = __float_as_int(sh[1]);
    grid.sync();

    if (blockIdx.x == 0 && tid == 0) {
        int list[XCDS]; int nz = 0;
        for (int j = 0; j < XCDS; ++j) {
            owncnt[j] = 0;
            if (__hip_atomic_load(&regcnt[j], __ATOMIC_RELAXED,
                                  __HIP_MEMORY_SCOPE_AGENT) > 0) list[nz++] = j;
        }
        int rr = 0;
        for (int j = 0; j < XCDS; ++j) {
            int present = __hip_atomic_load(&regcnt[j], __ATOMIC_RELAXED,
                                            __HIP_MEMORY_SCOPE_AGENT) > 0;
            int owner = present ? j : list[rr++ % nz];
            owngrp[owner * 8 + owncnt[owner]] = j;
            owncnt[owner] += 1;
        }
    }
    grid.sync();

    int nblk = __hip_atomic_load(&regcnt[xcd], __ATOMIC_RELAXED, __HIP_MEMORY_SCOPE_AGENT);
    int nown = owncnt[xcd];

    int wave = tid >> 6;
    int lane = tid & 63;
    int rs   = lane >> 3;
    int u    = lane & 7;

    // half assignment (robust to nblk==1)
    int hfbeg, hfend, mywave, nwh;
    if (nblk >= 2) {
        int hf = slot & 1;
        hfbeg = hf; hfend = hf + 1;
        int nhb = (hf == 0) ? ((nblk + 1) >> 1) : (nblk >> 1);
        mywave = (slot >> 1) * (RNN_THREADS / 64) + wave;
        nwh = nhb * (RNN_THREADS / 64);
    } else {
        hfbeg = 0; hfend = 2;
        mywave = wave; nwh = RNN_THREADS / 64;
    }

    // ---- hoist t-invariant CSR metadata; registerize hhpack windows ----
    int g0 = mywave, g1 = mywave + nwh;
    bool valid0 = g0 < (H_ / 8), valid1 = g1 < (H_ / 8);
    int r0 = g0 * 8 + rs, r1 = g1 * 8 + rs;
    int hb0 = 0, len0 = 0, hb1 = 0, len1 = 0;
    if (valid0) { hb0 = hhp[r0]; len0 = hhp[r0 + 1] - hb0; }
    if (valid1) { hb1 = hhp[r1]; len1 = hhp[r1 + 1] - hb1; }
    int lmax0 = len0, lmax1 = len1;
    lmax0 = max(lmax0, __shfl_xor(lmax0, 8));
    lmax0 = max(lmax0, __shfl_xor(lmax0, 16));
    lmax0 = max(lmax0, __shfl_xor(lmax0, 32));
    lmax0 = __builtin_amdgcn_readfirstlane(lmax0);
    lmax1 = max(lmax1, __shfl_xor(lmax1, 8));
    lmax1 = max(lmax1, __shfl_xor(lmax1, 16));
    lmax1 = max(lmax1, __shfl_xor(lmax1, 32));
    lmax1 = __builtin_amdgcn_readfirstlane(lmax1);

    int   pcol0[MAXIT_HH]; float pval0[MAXIT_HH];
    int   pcol1[MAXIT_HH]; float pval1[MAXIT_HH];
    #pragma unroll
    for (int it = 0; it < MAXIT_HH; ++it) {
        int2 pk = make_int2(0, 0);
        if (it * 8 + u < len0) pk = hhpack[hb0 + it * 8 + u];
        pcol0[it] = pk.x << 4;               // byte offset into sh (float4)
        pval0[it] = __int_as_float(pk.y);
    }
    #pragma unroll
    for (int it = 0; it < MAXIT_HH; ++it) {
        int2 pk = make_int2(0, 0);
        if (it * 8 + u < len1) pk = hhpack[hb1 + it * 8 + u];
        pcol1[it] = pk.x << 4;
        pval1[it] = __int_as_float(pk.y);
    }
    bool dyn = (mywave + 2 * nwh) < (H_ / 8);   // rare (uneven dispatch only)

    int* bc = &barcnt[xcd * 32];
    int* bgen = &bargen[xcd * 32];

    for (int t = 0; t < T_; ++t) {
        for (int oi = 0; oi < nown; ++oi) {
            int grp = owngrp[xcd * 8 + oi];
            for (int hf = hfbeg; hf < hfend; ++hf) {
                const float* src = hg + (size_t)((grp * 2 + (t & 1)) * 2 + hf) * (H_ * 4);
                float*       dst = hg + (size_t)((grp * 2 + ((t + 1) & 1)) * 2 + hf) * (H_ * 4);
                const unsigned short* preb =
                    pre + ((size_t)(grp * 2 + hf) * T_ + t) * (H_ * 4);

                // prefetch pre (consumed after reduce; latency overlaps fill+barrier)
                unsigned short pus0 = 0, pus1 = 0;
                if (u < 4) {
                    if (valid0) pus0 = preb[(size_t)r0 * 4 + u];
                    if (valid1) pus1 = preb[(size_t)r1 * 4 + u];
                }

                // ---- fill sh with h_prev (sc0: bypass stale L1, hit local L2) ----
                __syncthreads();   // prior readers of sh are done
                {
                    float4 v0, v1, v2, v3;
                    const float* p0 = src + (size_t)(0 * 1024 + tid) * 4;
                    const float* p1 = src + (size_t)(1 * 1024 + tid) * 4;
                    const float* p2 = src + (size_t)(2 * 1024 + tid) * 4;
                    const float* p3 = src + (size_t)(3 * 1024 + tid) * 4;
                    load4x16_sc0(p0, p1, p2, p3, v0, v1, v2, v3);
                    float4* s4 = (float4*)sh;
                    s4[0 * 1024 + tid] = v0;
                    s4[1 * 1024 + tid] = v1;
                    s4[2 * 1024 + tid] = v2;
                    s4[3 * 1024 + tid] = v3;
                }
                __syncthreads();   // sh ready

                // ---- compute: registerized hh SpMM + pre + tanh ----
                float h0val = 0.f, h1val = 0.f;
                if (valid0) {
                    float a0 = 0.f, a1 = 0.f, a2 = 0.f, a3 = 0.f;
                    #pragma unroll
                    for (int it = 0; it < MAXIT_HH; ++it) {
                        float4 hv = *(const float4*)((const char*)sh + pcol0[it]);
                        float v = pval0[it];
                        a0 += v * hv.x; a1 += v * hv.y; a2 += v * hv.z; a3 += v * hv.w;
                    }
                    if (lmax0 > 8 * MAXIT_HH) {
                        int kk = hb0 + 8 * MAXIT_HH + u;
                        for (int i = 8 * MAXIT_HH; i < lmax0; i += 8, kk += 8) {
                            int2 pk = make_int2(0, 0);
                            if (i + u < len0) pk = hhpack[kk];
                            float4 hv = *(const float4*)((const char*)sh + ((size_t)pk.x << 4));
                            float v = __int_as_float(pk.y);
                            a0 += v * hv.x; a1 += v * hv.y; a2 += v * hv.z; a3 += v * hv.w;
                        }
                    }
                    #pragma unroll
                    for (int off = 1; off <= 4; off <<= 1) {
                        a0 += __shfl_xor(a0, off);
                        a1 += __shfl_xor(a1, off);
                        a2 += __shfl_xor(a2, off);
                        a3 += __shfl_xor(a3, off);
                    }
                    if (u < 4) {
                        float acc = (u == 0) ? a0 : (u == 1) ? a1 : (u == 2) ? a2 : a3;
                        float pv = __uint_as_float((unsigned int)pus0 << 16);
                        h0val = tanhf(acc + pv);
                    }
                }
                if (valid1) {
                    float a0 = 0.f, a1 = 0.f, a2 = 0.f, a3 = 0.f;
                    #pragma unroll
                    for (int it = 0; it < MAXIT_HH; ++it) {
                        float4 hv = *(const float4*)((const char*)sh + pcol1[it]);
                        float v = pval1[it];
                        a0 += v * hv.x; a1 += v * hv.y; a2 += v * hv.z; a3 += v * hv.w;
                    }
                    if (lmax1 > 8 * MAXIT_HH) {
                        int kk = hb1 + 8 * MAXIT_HH + u;
                        for (int i = 8 * MAXIT_HH; i < lmax1; i += 8, kk += 8) {
                            int2 pk = make_int2(0, 0);
                            if (i + u < len1) pk = hhpack[kk];
                            float4 hv = *(const float4*)((const char*)sh + ((size_t)pk.x << 4));
                            float v = __int_as_float(pk.y);
                            a0 += v * hv.x; a1 += v * hv.y; a2 += v * hv.z; a3 += v * hv.w;
                        }
                    }
                    #pragma unroll
                    for (int off = 1; off <= 4; off <<= 1) {
                        a0 += __shfl_xor(a0, off);
                        a1 += __shfl_xor(a1, off);
                        a2 += __shfl_xor(a2, off);
                        a3 += __shfl_xor(a3, off);
                    }
                    if (u < 4) {
                        float acc = (u == 0) ? a0 : (u == 1) ? a1 : (u == 2) ? a2 : a3;
                        float pv = __uint_as_float((unsigned int)pus1 << 16);
                        h1val = tanhf(acc + pv);
                    }
                }
                if (dyn) {   // rare: >2 row-groups/wave (uneven dispatch) — dynamic path
                    for (int g = mywave + 2 * nwh; g < H_ / 8; g += nwh) {
                        int r  = g * 8 + rs;
                        int hb = hhp[r], he = hhp[r + 1];
                        int len = he - hb;
                        int lmax = len;
                        lmax = max(lmax, __shfl_xor(lmax, 8));
                        lmax = max(lmax, __shfl_xor(lmax, 16));
                        lmax = max(lmax, __shfl_xor(lmax, 32));
                        float a0 = 0.f, a1 = 0.f, a2 = 0.f, a3 = 0.f;
                        int kk = hb + u;
                        for (int i = 0; i < lmax; i += 8, kk += 8) {
                            int2 pk = make_int2(0, 0);
                            if (i + u < len) pk = hhpack[kk];
                            float4 hv = *(const float4*)((const char*)sh + ((size_t)pk.x << 4));
                            float v = __int_as_float(pk.y);
                            a0 += v * hv.x; a1 += v * hv.y; a2 += v * hv.z; a3 += v * hv.w;
                        }
                        #pragma unroll
                        for (int off = 1; off <= 4; off <<= 1) {
                            a0 += __shfl_xor(a0, off);
                            a1 += __shfl_xor(a1, off);
                            a2 += __shfl_xor(a2, off);
                            a3 += __shfl_xor(a3, off);
                        }
                        if (u < 4) {
                            float acc = (u == 0) ? a0 : (u == 1) ? a1 : (u == 2) ? a2 : a3;
                            float pv = __uint_as_float(
                                (unsigned int)preb[(size_t)r * 4 + u] << 16);
                            float h = tanhf(acc + pv);
                            dst[(size_t)r * 4 + u] = h;
                            int b = grp * 8 + hf * 4 + u;
                            out[(size_t)b * T_ * H_ + (size_t)t * H_ + r] = h;
                        }
                    }
                }

                if (u < 4) {
                    if (valid0) {
                        dst[(size_t)r0 * 4 + u] = h0val;
                        int b = grp * 8 + hf * 4 + u;
                        out[(size_t)b * T_ * H_ + (size_t)t * H_ + r0] = h0val;
                    }
                    if (valid1) {
                        dst[(size_t)r1 * 4 + u] = h1val;
                        int b = grp * 8 + hf * 4 + u;
                        out[(size_t)b * T_ * H_ + (size_t)t * H_ + r1] = h1val;
                    }
                }
            }
        }

        // ---- per-XCD barrier (round-0 proven protocol: full drain) ----
        __syncthreads();   // drains this block's h stores to L2 (vmcnt(0) before s_barrier)
        if (tid == 0) {
            asm volatile("s_waitcnt vmcnt(0)" ::: "memory");
            int target = t + 1;
            int old = __hip_atomic_fetch_add(bc, 1, __ATOMIC_RELAXED,
                                             __HIP_MEMORY_SCOPE_AGENT);
            if (old == nblk - 1) {
                __hip_atomic_store(bc, 0, __ATOMIC_RELAXED, __HIP_MEMORY_SCOPE_AGENT);
                __hip_atomic_store(bgen, target, __ATOMIC_RELAXED, __HIP_MEMORY_SCOPE_AGENT);
            } else {
                while (__hip_atomic_load(bgen, __ATOMIC_RELAXED,
                                         __HIP_MEMORY_SCOPE_AGENT) < target) {
                    __builtin_amdgcn_s_sleep(1);
                }
            }
        }
        __syncthreads();
    }
}

// ---------------- host launch ----------------
extern "C" void kernel_launch(void* const* d_in, const int* in_sizes, int n_in,
                              void* d_out, int out_size, void* d_ws, size_t ws_size,
                              hipStream_t stream) {
    const float* x       = (const float*)d_in[0];
    const float* ih_vals = (const float*)d_in[1];
    const float* hh_vals = (const float*)d_in[2];
    const float* hh_bias = (const float*)d_in[3];
    const int*   ih_rows = (const int*)d_in[4];
    const int*   ih_cols = (const int*)d_in[5];
    const int*   hh_rows = (const int*)d_in[6];
    const int*   hh_cols = (const int*)d_in[7];
    float* out = (float*)d_out;

    const int nnz_ih = in_sizes[1];
    const int nnz_hh = in_sizes[2];

    char* ws = (char*)d_ws;
    size_t off = 0;
    auto alloc = [&](size_t bytes) -> void* {
        off = (off + 255) & ~(size_t)255;
        void* p = ws + off;
        off += bytes;
        return p;
    };

    float* xT2   = (float*)alloc((size_t)T_ * 8 * I_ * 8 * sizeof(float));
    int*   ih_rp = (int*)  alloc((H_ + 1) * sizeof(int));
    int*   hh_rp = (int*)  alloc((H_ + 1) * sizeof(int));

    const int ZINTS = 4 * H_ + 64 + 8 * 32 + 8 * 32 + 8 + 64;
    int* zbase  = (int*)alloc((size_t)ZINTS * sizeof(int));
    int* ih_cnt = zbase;
    int* ih_cur = zbase + H_;
    int* hh_cnt = zbase + 2 * H_;
    int* hh_cur = zbase + 3 * H_;
    int* regcnt = zbase + 4 * H_;
    int* barcnt = regcnt + 64;
    int* bargen = barcnt + 8 * 32;
    int* owncnt = bargen + 8 * 32;
    int* owngrp = owncnt + 8;

    int2* ih_pack = (int2*)alloc((size_t)nnz_ih * sizeof(int2));
    int2* hh_pack = (int2*)alloc((size_t)nnz_hh * sizeof(int2));
    float* hg     = (float*)alloc((size_t)XCDS * 2 * 2 * H_ * 4 * sizeof(float));  // 2 MB
    unsigned short* pre = (unsigned short*)alloc((size_t)16 * T_ * H_ * 4 * sizeof(unsigned short)); // 67 MB

    hipMemsetAsync(zbase, 0, (size_t)ZINTS * sizeof(int), stream);
    hipMemsetAsync(hg, 0, (size_t)XCDS * 2 * 2 * H_ * 4 * sizeof(float), stream);

    transpose_x<<<dim3(I_ / 128, 8, T_), dim3(128, 8), 0, stream>>>(x, xT2);

    hist_rows<<<(nnz_ih + 255) / 256, 256, 0, stream>>>(ih_rows, nnz_ih, ih_cnt);
    scan_rows<<<1, 64, 0, stream>>>(ih_cnt, ih_rp, H_);
    scatter_pack<<<(nnz_ih + 255) / 256, 256, 0, stream>>>(ih_rows, ih_cols, ih_vals, nnz_ih,
                                                           ih_rp, ih_cur, ih_pack);
    hist_rows<<<(nnz_hh + 255) / 256, 256, 0, stream>>>(hh_rows, nnz_hh, hh_cnt);
    scan_rows<<<1, 64, 0, stream>>>(hh_cnt, hh_rp, H_);
    scatter_pack<<<(nnz_hh + 255) / 256, 256, 0, stream>>>(hh_rows, hh_cols, hh_vals, nnz_hh,
                                                           hh_rp, hh_cur, hh_pack);

    precompute_ih<<<dim3(H_ / 64, 8), dim3(256), 0, stream>>>(xT2, ih_rp, ih_pack,
                                                              hh_bias, pre);

    void* kargs[] = {
        (void*)&hh_rp, (void*)&hh_pack,
        (void*)&pre,
        (void*)&hg,
        (void*)&regcnt, (void*)&barcnt, (void*)&bargen,
        (void*)&owncnt, (void*)&owngrp,
        (void*)&out,
    };
    hipLaunchCooperativeKernel((const void*)rnn_steps, dim3(RNN_BLOCKS), dim3(RNN_THREADS),
                               kargs, 0, stream);
}

// Round 3
// 1762.222 us; speedup vs baseline: 1.2994x; 1.2994x over previous
//
#include <hip/hip_runtime.h>
#include <hip/hip_cooperative_groups.h>
#include <math.h>

namespace cg = cooperative_groups;

#define B_ 64
#define T_ 128
#define I_ 1024
#define H_ 4096
#define XCDS 8

#define RNN_BLOCKS 256
#define RNN_THREADS 1024

#define MAXIT_IH 8    // 64 nnz/row registerized (Poisson(32)); tail fallback beyond

// ---------------- helpers ----------------
__device__ __forceinline__ unsigned short f2bf(float f) {
    unsigned int u = __float_as_uint(f);
    unsigned int r = (u + 0x7fffu + ((u >> 16) & 1u)) >> 16;
    return (unsigned short)r;
}

__device__ __forceinline__ void load4x16_sc0(const float* p0, const float* p1,
                                             const float* p2, const float* p3,
                                             float4& a, float4& b, float4& c, float4& d) {
    asm volatile(
        "global_load_dwordx4 %0, %4, off sc0\n\t"
        "global_load_dwordx4 %1, %5, off sc0\n\t"
        "global_load_dwordx4 %2, %6, off sc0\n\t"
        "global_load_dwordx4 %3, %7, off sc0\n\t"
        "s_waitcnt vmcnt(0)"
        : "=&v"(a), "=&v"(b), "=&v"(c), "=&v"(d)
        : "v"(p0), "v"(p1), "v"(p2), "v"(p3));
}

// ---------------- transpose x (B,T,I) -> xT2 (T, 8, I, 8) ----------------
__global__ void transpose_x(const float* __restrict__ x, float* __restrict__ xT2) {
    __shared__ float lds[8][129];
    int t  = blockIdx.z;
    int bg = blockIdx.y;
    int i0 = blockIdx.x * 128;
    int tx = threadIdx.x;   // 0..127
    int ty = threadIdx.y;   // 0..7
    int b = bg * 8 + ty;
    lds[ty][tx] = x[(size_t)b * T_ * I_ + (size_t)t * I_ + i0 + tx];
    __syncthreads();
    int n  = ty * 128 + tx;
    int ii = n >> 3;
    int bs = n & 7;
    xT2[(((size_t)t * 8 + bg) * I_ + i0 + ii) * 8 + bs] = lds[bs][ii];
}

// ---------------- CSR build ----------------
__global__ void hist_rows(const int* __restrict__ rows, int nnz, int* __restrict__ counts) {
    int k = blockIdx.x * blockDim.x + threadIdx.x;
    if (k < nnz) atomicAdd(&counts[rows[k]], 1);
}

__global__ void scan_rows(const int* __restrict__ counts, int* __restrict__ rp, int n) {
    int lane = threadIdx.x;      // 0..63
    int chunk = n / 64;
    int base = lane * chunk;
    int s = 0;
    for (int j = 0; j < chunk; ++j) s += counts[base + j];
    int pre = s;
    for (int off = 1; off < 64; off <<= 1) {
        int up = __shfl_up(pre, off, 64);
        if (lane >= off) pre += up;
    }
    int run = pre - s;
    for (int j = 0; j < chunk; ++j) { rp[base + j] = run; run += counts[base + j]; }
    if (lane == 63) rp[n] = run;
}

__global__ void scatter_pack(const int* __restrict__ rows, const int* __restrict__ cols,
                             const float* __restrict__ vals, int nnz,
                             const int* __restrict__ rp, int* __restrict__ cursor,
                             int2* __restrict__ pack) {
    int k = blockIdx.x * blockDim.x + threadIdx.x;
    if (k < nnz) {
        int r = rows[k];
        int pos = atomicAdd(&cursor[r], 1);
        pack[rp[r] + pos] = make_int2(cols[k], __float_as_int(vals[k]));
    }
}

// ---------------- kernel P: pre[t] = W_ih * x_t + bias  (bf16 out) ----------------
// One block per (4 row-groups, grp); t-loop inside. CSR slices registerized
// (t-invariant), x_t slice staged in LDS (32 KB), 1 row-group per wave.
__global__ __launch_bounds__(256)
void precompute_ih(const float* __restrict__ xT2,
                   const int* __restrict__ rp, const int2* __restrict__ pack,
                   const float* __restrict__ bias,
                   unsigned short* __restrict__ pre) {
    __shared__ __align__(16) float xs[I_ * 8];   // 32 KB: x_t slice for this grp
    int grp  = blockIdx.y;
    int wave = threadIdx.x >> 6;                  // 0..3
    int lane = threadIdx.x & 63;
    int rs = lane >> 3;   // row within group
    int u  = lane & 7;    // position within window

    int g = blockIdx.x * 4 + wave;                // 0..511
    int r = g * 8 + rs;
    int hb = rp[r];
    int len = rp[r + 1] - hb;
    int lm = len;
    lm = max(lm, __shfl_xor(lm, 8));
    lm = max(lm, __shfl_xor(lm, 16));
    lm = max(lm, __shfl_xor(lm, 32));
    int lmax = __builtin_amdgcn_readfirstlane(lm);
    float bsv = bias[r];

    // registerize the CSR slice (t-invariant): byte offsets pre-shifted
    int   pcol[MAXIT_IH];
    float pval[MAXIT_IH];
    #pragma unroll
    for (int it = 0; it < MAXIT_IH; ++it) {
        int2 pk = make_int2(0, 0);
        if (it * 8 + u < len) pk = pack[hb + it * 8 + u];
        pcol[it] = pk.x << 5;                 // col * 8 floats * 4 B
        pval[it] = __int_as_float(pk.y);
    }

    for (int t = 0; t < T_; ++t) {
        const float* xt = xT2 + ((size_t)t * 8 + grp) * (I_ * 8);
        __syncthreads();    // prior step's reads of xs done
        {
            const float4* s = (const float4*)xt;
            float4* d = (float4*)xs;
            #pragma unroll
            for (int j = 0; j < 8; ++j)
                d[j * 256 + threadIdx.x] = s[j * 256 + threadIdx.x];
        }
        __syncthreads();    // xs ready

        float a[8];
        #pragma unroll
        for (int j = 0; j < 8; ++j) a[j] = 0.0f;

        // branchless registerized windows (padded lanes read xs[0], add +0.0)
        #pragma unroll
        for (int it = 0; it < MAXIT_IH; ++it) {
            const float* gp = (const float*)((const char*)xs + pcol[it]);
            float4 x0 = *(const float4*)gp;
            float4 x1 = *(const float4*)(gp + 4);
            float v = pval[it];
            a[0] += v * x0.x; a[1] += v * x0.y; a[2] += v * x0.z; a[3] += v * x0.w;
            a[4] += v * x1.x; a[5] += v * x1.y; a[6] += v * x1.z; a[7] += v * x1.w;
        }
        if (lmax > 8 * MAXIT_IH) {   // rare tail, same summation order
            int kk = hb + 8 * MAXIT_IH + u;
            for (int i = 8 * MAXIT_IH; i < lmax; i += 8, kk += 8) {
                int2 pk = make_int2(0, 0);
                if (i + u < len) pk = pack[kk];
                const float* gp = (const float*)((const char*)xs + ((size_t)pk.x << 5));
                float4 x0 = *(const float4*)gp;
                float4 x1 = *(const float4*)(gp + 4);
                float v = __int_as_float(pk.y);
                a[0] += v * x0.x; a[1] += v * x0.y; a[2] += v * x0.z; a[3] += v * x0.w;
                a[4] += v * x1.x; a[5] += v * x1.y; a[6] += v * x1.z; a[7] += v * x1.w;
            }
        }
        #pragma unroll
        for (int off = 1; off <= 4; off <<= 1) {
            #pragma unroll
            for (int j = 0; j < 8; ++j) a[j] += __shfl_xor(a[j], off);
        }
        float sel = (u == 0) ? a[0] : (u == 1) ? a[1] : (u == 2) ? a[2] : (u == 3) ? a[3]
                  : (u == 4) ? a[4] : (u == 5) ? a[5] : (u == 6) ? a[6] : a[7];
        float p = sel + bsv;
        int hf = u >> 2, cc = u & 3;
        pre[((size_t)(grp * 2 + hf) * T_ + t) * (H_ * 4) + (size_t)r * 4 + cc] = f2bf(p);
    }
}

// ---------------- kernel R: persistent XCD-local recurrence ----------------
// EXACT round-0 version (proven 1130 us, FETCH 43 MB — L2-resident hg).
// hg layout: hg[((grp*2 + parity)*2 + half) * (H_*4)]
__global__ __launch_bounds__(RNN_THREADS, 1)
void rnn_steps(const int* __restrict__ hhp, const int2* __restrict__ hhpack,
               const unsigned short* __restrict__ pre,
               float* __restrict__ hg,
               int* __restrict__ regcnt, int* __restrict__ barcnt, int* __restrict__ bargen,
               int* __restrict__ owncnt, int* __restrict__ owngrp,
               float* __restrict__ out) {
    cg::grid_group grid = cg::this_grid();
    __shared__ __align__(16) float sh[H_ * 4];   // 64 KB: h_prev, 4 batch cols of this half

    int tid = threadIdx.x;
    if (tid == 0) {
        int x;
        asm volatile("s_getreg_b32 %0, hwreg(HW_REG_XCC_ID)" : "=s"(x));
        x &= 7;
        int slot = __hip_atomic_fetch_add(&regcnt[x], 1, __ATOMIC_RELAXED,
                                          __HIP_MEMORY_SCOPE_AGENT);
        sh[0] = __int_as_float(x);
        sh[1] = __int_as_float(slot);
    }
    __syncthreads();
    int xcd  = __float_as_int(sh[0]);
    int slot = __float_as_int(sh[1]);
    grid.sync();

    if (blockIdx.x == 0 && tid == 0) {
        int list[XCDS]; int nz = 0;
        for (int j = 0; j < XCDS; ++j) {
            owncnt[j] = 0;
            if (__hip_atomic_load(&regcnt[j], __ATOMIC_RELAXED,
                                  __HIP_MEMORY_SCOPE_AGENT) > 0) list[nz++] = j;
        }
        int rr = 0;
        for (int j = 0; j < XCDS; ++j) {
            int present = __hip_atomic_load(&regcnt[j], __ATOMIC_RELAXED,
                                            __HIP_MEMORY_SCOPE_AGENT) > 0;
            int owner = present ? j : list[rr++ % nz];
            owngrp[owner * 8 + owncnt[owner]] = j;
            owncnt[owner] += 1;
        }
    }
    grid.sync();

    int nblk = __hip_atomic_load(&regcnt[xcd], __ATOMIC_RELAXED, __HIP_MEMORY_SCOPE_AGENT);
    int nown = owncnt[xcd];

    int wave = tid >> 6;
    int lane = tid & 63;
    int rs   = lane >> 3;
    int u    = lane & 7;

    // half assignment (robust to nblk==1)
    int hfbeg, hfend, mywave, nwh;
    if (nblk >= 2) {
        int hf = slot & 1;
        hfbeg = hf; hfend = hf + 1;
        int nhb = (hf == 0) ? ((nblk + 1) >> 1) : (nblk >> 1);
        mywave = (slot >> 1) * (RNN_THREADS / 64) + wave;
        nwh = nhb * (RNN_THREADS / 64);
    } else {
        hfbeg = 0; hfend = 2;
        mywave = wave; nwh = RNN_THREADS / 64;
    }

    int* bc = &barcnt[xcd * 32];
    int* bgen = &bargen[xcd * 32];

    for (int t = 0; t < T_; ++t) {
        for (int oi = 0; oi < nown; ++oi) {
            int grp = owngrp[xcd * 8 + oi];
            for (int hf = hfbeg; hf < hfend; ++hf) {
                const float* src = hg + (size_t)((grp * 2 + (t & 1)) * 2 + hf) * (H_ * 4);
                float*       dst = hg + (size_t)((grp * 2 + ((t + 1) & 1)) * 2 + hf) * (H_ * 4);

                // ---- fill sh with h_prev (sc0: bypass stale L1, hit local L2) ----
                __syncthreads();   // prior readers of sh are done
                {
                    float4 v0, v1, v2, v3;
                    const float* p0 = src + (size_t)(0 * 1024 + tid) * 4;
                    const float* p1 = src + (size_t)(1 * 1024 + tid) * 4;
                    const float* p2 = src + (size_t)(2 * 1024 + tid) * 4;
                    const float* p3 = src + (size_t)(3 * 1024 + tid) * 4;
                    load4x16_sc0(p0, p1, p2, p3, v0, v1, v2, v3);
                    float4* s4 = (float4*)sh;
                    s4[0 * 1024 + tid] = v0;
                    s4[1 * 1024 + tid] = v1;
                    s4[2 * 1024 + tid] = v2;
                    s4[3 * 1024 + tid] = v3;
                }
                __syncthreads();   // sh ready

                // ---- compute: hh SpMM rows + pre + tanh ----
                for (int g = mywave; g < H_ / 8; g += nwh) {
                    int r  = g * 8 + rs;
                    int hb = hhp[r], he = hhp[r + 1];
                    int len = he - hb;
                    int lmax = len;
                    lmax = max(lmax, __shfl_xor(lmax, 8));
                    lmax = max(lmax, __shfl_xor(lmax, 16));
                    lmax = max(lmax, __shfl_xor(lmax, 32));

                    float a0 = 0.f, a1 = 0.f, a2 = 0.f, a3 = 0.f;
                    int kk = hb + u;
                    for (int i = 0; i < lmax; i += 8, kk += 8) {
                        int2 pk = make_int2(0, 0);
                        if (i + u < len) pk = hhpack[kk];
                        float4 hv = ((const float4*)sh)[pk.x];
                        float v = __int_as_float(pk.y);
                        a0 += v * hv.x; a1 += v * hv.y; a2 += v * hv.z; a3 += v * hv.w;
                    }
                    #pragma unroll
                    for (int off = 1; off <= 4; off <<= 1) {
                        a0 += __shfl_xor(a0, off);
                        a1 += __shfl_xor(a1, off);
                        a2 += __shfl_xor(a2, off);
                        a3 += __shfl_xor(a3, off);
                    }
                    if (u < 4) {
                        float acc = (u == 0) ? a0 : (u == 1) ? a1 : (u == 2) ? a2 : a3;
                        float pv = __uint_as_float(
                            (unsigned int)pre[((size_t)(grp * 2 + hf) * T_ + t) * (H_ * 4) +
                                              (size_t)r * 4 + u] << 16);
                        float h = tanhf(acc + pv);
                        dst[(size_t)r * 4 + u] = h;
                        int b = grp * 8 + hf * 4 + u;
                        out[(size_t)b * T_ * H_ + (size_t)t * H_ + r] = h;
                    }
                }
            }
        }

        // ---- per-XCD barrier (no cache maintenance) ----
        __syncthreads();   // drains this block's h stores to L2 (vmcnt(0) before s_barrier)
        if (tid == 0) {
            asm volatile("s_waitcnt vmcnt(0)" ::: "memory");
            int target = t + 1;
            int old = __hip_atomic_fetch_add(bc, 1, __ATOMIC_RELAXED,
                                             __HIP_MEMORY_SCOPE_AGENT);
            if (old == nblk - 1) {
                __hip_atomic_store(bc, 0, __ATOMIC_RELAXED, __HIP_MEMORY_SCOPE_AGENT);
                __hip_atomic_store(bgen, target, __ATOMIC_RELAXED, __HIP_MEMORY_SCOPE_AGENT);
            } else {
                while (__hip_atomic_load(bgen, __ATOMIC_RELAXED,
                                         __HIP_MEMORY_SCOPE_AGENT) < target) {
                    __builtin_amdgcn_s_sleep(1);
                }
            }
        }
        __syncthreads();
    }
}

// ---------------- host launch ----------------
extern "C" void kernel_launch(void* const* d_in, const int* in_sizes, int n_in,
                              void* d_out, int out_size, void* d_ws, size_t ws_size,
                              hipStream_t stream) {
    const float* x       = (const float*)d_in[0];
    const float* ih_vals = (const float*)d_in[1];
    const float* hh_vals = (const float*)d_in[2];
    const float* hh_bias = (const float*)d_in[3];
    const int*   ih_rows = (const int*)d_in[4];
    const int*   ih_cols = (const int*)d_in[5];
    const int*   hh_rows = (const int*)d_in[6];
    const int*   hh_cols = (const int*)d_in[7];
    float* out = (float*)d_out;

    const int nnz_ih = in_sizes[1];
    const int nnz_hh = in_sizes[2];

    char* ws = (char*)d_ws;
    size_t off = 0;
    auto alloc = [&](size_t bytes) -> void* {
        off = (off + 255) & ~(size_t)255;
        void* p = ws + off;
        off += bytes;
        return p;
    };

    float* xT2   = (float*)alloc((size_t)T_ * 8 * I_ * 8 * sizeof(float));
    int*   ih_rp = (int*)  alloc((H_ + 1) * sizeof(int));
    int*   hh_rp = (int*)  alloc((H_ + 1) * sizeof(int));

    const int ZINTS = 4 * H_ + 64 + 8 * 32 + 8 * 32 + 8 + 64;
    int* zbase  = (int*)alloc((size_t)ZINTS * sizeof(int));
    int* ih_cnt = zbase;
    int* ih_cur = zbase + H_;
    int* hh_cnt = zbase + 2 * H_;
    int* hh_cur = zbase + 3 * H_;
    int* regcnt = zbase + 4 * H_;
    int* barcnt = regcnt + 64;
    int* bargen = barcnt + 8 * 32;
    int* owncnt = bargen + 8 * 32;
    int* owngrp = owncnt + 8;

    int2* ih_pack = (int2*)alloc((size_t)nnz_ih * sizeof(int2));
    int2* hh_pack = (int2*)alloc((size_t)nnz_hh * sizeof(int2));
    float* hg     = (float*)alloc((size_t)XCDS * 2 * 2 * H_ * 4 * sizeof(float));  // 2 MB
    unsigned short* pre = (unsigned short*)alloc((size_t)16 * T_ * H_ * 4 * sizeof(unsigned short)); // 67 MB

    hipMemsetAsync(zbase, 0, (size_t)ZINTS * sizeof(int), stream);
    hipMemsetAsync(hg, 0, (size_t)XCDS * 2 * 2 * H_ * 4 * sizeof(float), stream);

    transpose_x<<<dim3(I_ / 128, 8, T_), dim3(128, 8), 0, stream>>>(x, xT2);

    hist_rows<<<(nnz_ih + 255) / 256, 256, 0, stream>>>(ih_rows, nnz_ih, ih_cnt);
    scan_rows<<<1, 64, 0, stream>>>(ih_cnt, ih_rp, H_);
    scatter_pack<<<(nnz_ih + 255) / 256, 256, 0, stream>>>(ih_rows, ih_cols, ih_vals, nnz_ih,
                                                           ih_rp, ih_cur, ih_pack);
    hist_rows<<<(nnz_hh + 255) / 256, 256, 0, stream>>>(hh_rows, nnz_hh, hh_cnt);
    scan_rows<<<1, 64, 0, stream>>>(hh_cnt, hh_rp, H_);
    scatter_pack<<<(nnz_hh + 255) / 256, 256, 0, stream>>>(hh_rows, hh_cols, hh_vals, nnz_hh,
                                                           hh_rp, hh_cur, hh_pack);

    precompute_ih<<<dim3(H_ / 32, 8), dim3(256), 0, stream>>>(xT2, ih_rp, ih_pack,
                                                              hh_bias, pre);

    void* kargs[] = {
        (void*)&hh_rp, (void*)&hh_pack,
        (void*)&pre,
        (void*)&hg,
        (void*)&regcnt, (void*)&barcnt, (void*)&bargen,
        (void*)&owncnt, (void*)&owngrp,
        (void*)&out,
    };
    hipLaunchCooperativeKernel((const void*)rnn_steps, dim3(RNN_BLOCKS), dim3(RNN_THREADS),
                               kargs, 0, stream);
}